// Round 20
// baseline (246.959 us; speedup 1.0000x reference)
//
#include <hip/hip_runtime.h>
#include <hip/hip_fp16.h>

#define NN 100000
#define NE 3200000
#define NG 2048
#define HD 64
#define BUKSZ 256         // nodes per bucket
#define NBUK 391          // ceil(NN / BUKSZ)
#define NB 512            // stage blocks
#define CHUNK 6250        // NE / NB exactly
#define CAP 9216          // padded edge capacity per bucket

// NOTE: int LDS atomics only. Float LDS atomicAdd is a CAS loop (R8: 1342us).
// NOTE2 (R9): latency-bound gathers want max independent waves.
// NOTE3 (R11): shfl with divergent srcLane under divergent bounds is undefined.
// NOTE4 (R15): 16B/lane loads: 4 rows per VMEM instr.
// NOTE5 (R16): >16-float per-thread arrays spill to scratch (205MB = 60us).
// NOTE6 (R17): readlane-GEMM is VALU-issue-bound; MFMA = 8 ops/wave (R18: -28us).
// NOTE7 (R19): packed fp16 accumulation removes cvt from gather inner loop.
// NOTE8 (R20): gather is L2-miss-bound (h1 12.8MB > 4MB XCD-L2, 8x replication).
// Chunk-major h1c[c][node][16] + chunk=blockIdx&3 pins one 3.2MB slice per XCD.

typedef __attribute__((ext_vector_type(8))) _Float16 f16x8;
typedef __attribute__((ext_vector_type(4))) float f32x4;
union I4H8 { int4 i4; f16x8 h8; };

// ---------------- init per-bucket cursors (absolute) ----------------

__global__ void init_k(int* __restrict__ bcur) {
    int t = blockIdx.x * blockDim.x + threadIdx.x;
    if (t <= NBUK) bcur[t] = t * CAP;
}

// ---------------- W2 -> transposed fp16 (W2t[n][k]) ----------------

__global__ void w2t_k(const float* __restrict__ W2, _Float16* __restrict__ W2t) {
    int t = blockIdx.x * blockDim.x + threadIdx.x;
    if (t < HD * HD) {
        int n = t >> 6, k = t & 63;
        W2t[n * HD + k] = (_Float16)W2[k * HD + n];
    }
}

// ---------------- pass 1: block-local bucket sort -> padded bucket runs ----------------
// packed value: (dst & 255) << 17 | src   (src < 2^17)

__global__ __launch_bounds__(512) void stageA_k(
        const int* __restrict__ src, const int* __restrict__ dst,
        int* __restrict__ bcur, unsigned int* __restrict__ edges2) {
    __shared__ int hist[NBUK];
    __shared__ int exb[NBUK + 1];
    __shared__ int cur[NBUK];
    __shared__ int obase[NBUK];
    __shared__ int sc[512];
    __shared__ unsigned int svals[CHUNK];
    __shared__ unsigned short sbuk[CHUNK];   // bucket id per sorted slot
    int b = blockIdx.x, t = threadIdx.x;
    int base = b * CHUNK;
    for (int i = t; i < NBUK; i += 512) hist[i] = 0;
    __syncthreads();
    for (int i = t; i < CHUNK; i += 512)
        atomicAdd(&hist[dst[base + i] >> 8], 1);
    __syncthreads();
    int v = (t < NBUK) ? hist[t] : 0;
    sc[t] = v;
    __syncthreads();
    for (int o = 1; o < 512; o <<= 1) {
        int u = (t >= o) ? sc[t - o] : 0;
        __syncthreads();
        sc[t] += u;
        __syncthreads();
    }
    if (t < NBUK) {
        int excl = sc[t] - v;
        exb[t] = excl;
        cur[t] = excl;
        obase[t] = v ? atomicAdd(&bcur[t], v) : 0;
    }
    if (t == 0) exb[NBUK] = CHUNK;
    __syncthreads();
    for (int i = t; i < CHUNK; i += 512) {
        int d = dst[base + i];
        int s = src[base + i];
        int bk = d >> 8;
        int pos = atomicAdd(&cur[bk], 1);
        svals[pos] = ((unsigned int)(d & 255) << 17) | (unsigned int)s;
        sbuk[pos] = (unsigned short)bk;
    }
    __syncthreads();
    for (int i = t; i < CHUNK; i += 512) {
        int lo = (int)sbuk[i];
        edges2[obase[lo] + (i - exb[lo])] = svals[i];
    }
}

// ---------------- pass 2: per-bucket fine sort (in-place) + row info + dinv + xs ----------------

__global__ __launch_bounds__(512) void build1_k(
        const int* __restrict__ bcur, const float4* __restrict__ x,
        unsigned int* __restrict__ edges2, int* __restrict__ row_beg,
        int* __restrict__ row_deg, float* __restrict__ dinv,
        float4* __restrict__ xs) {
    __shared__ unsigned int ebuf[CAP];   // 36 KB
    __shared__ int deg[BUKSZ];
    __shared__ int sc[BUKSZ];
    __shared__ int cur[BUKSZ];
    int k = blockIdx.x, t = threadIdx.x;
    int base = k * CAP;
    int len = bcur[k] - base;
    if (t < BUKSZ) deg[t] = 0;
    __syncthreads();
    for (int i = t; i < len; i += 512) {
        unsigned int pv = edges2[base + i];
        ebuf[i] = pv;
        atomicAdd(&deg[pv >> 17], 1);
    }
    __syncthreads();
    int v = 0;
    if (t < BUKSZ) { v = deg[t]; sc[t] = v; }
    __syncthreads();
    for (int o = 1; o < BUKSZ; o <<= 1) {
        int u = 0;
        if (t < BUKSZ && t >= o) u = sc[t - o];
        __syncthreads();
        if (t < BUKSZ && t >= o) sc[t] += u;
        __syncthreads();
    }
    if (t < BUKSZ) {
        int excl = sc[t] - v;
        cur[t] = excl;
        int node = k * BUKSZ + t;
        if (node < NN) {
            row_beg[node] = base + excl;
            row_deg[node] = v;
            float di = rsqrtf((float)v + 1.0f);
            dinv[node] = di;
            float4 xv = x[node];
            xs[node] = make_float4(xv.x * di, xv.y * di, xv.z * di, xv.w * di);
        }
    }
    __syncthreads();
    for (int i = t; i < len; i += 512) {
        unsigned int pv = ebuf[i];
        int pos = atomicAdd(&cur[pv >> 17], 1);
        edges2[base + pos] = pv & 0x1FFFFu;
    }
}

// ---------------- layer 1 FUSED: wave-per-node gather + W1 GEMM -> fp16 h1c ----------------
// h1c chunk-major: h1c[(lane>>4)*NN*16 + node*16 + (lane&15)]

__global__ __launch_bounds__(256) void g1f_k(
        const float4* __restrict__ xs, const unsigned int* __restrict__ csr,
        const int* __restrict__ row_beg, const int* __restrict__ row_deg,
        const float* __restrict__ dinv, const float* __restrict__ W1,
        const float* __restrict__ b1, __half* __restrict__ h1c) {
    int wid = (blockIdx.x * blockDim.x + threadIdx.x) >> 6;
    int lane = threadIdx.x & 63;
    if (wid >= NN) return;
    int beg = row_beg[wid], deg = row_deg[wid];
    float sx = 0.f, sy = 0.f, sz = 0.f, sw = 0.f;
    for (int e = beg + lane; e < beg + deg; e += 64) {
        float4 w = xs[csr[e]];
        sx += w.x; sy += w.y; sz += w.z; sw += w.w;
    }
#pragma unroll
    for (int o = 1; o < 64; o <<= 1) {
        sx += __shfl_xor(sx, o);
        sy += __shfl_xor(sy, o);
        sz += __shfl_xor(sz, o);
        sw += __shfl_xor(sw, o);
    }
    float di = dinv[wid];
    float4 self = xs[wid];
    float ax = (sx + self.x) * di;
    float ay = (sy + self.y) * di;
    float az = (sz + self.z) * di;
    float aw = (sw + self.w) * di;
    float v = ax * W1[lane] + ay * W1[64 + lane] + az * W1[128 + lane] + aw * W1[192 + lane] + b1[lane];
    v = fmaxf(v, 0.f) * di;
    h1c[(size_t)(lane >> 4) * NN * 16 + (size_t)wid * 16 + (lane & 15)] = __float2half_rn(v);
}

// ---------------- layer 2 gather: chunk-partitioned (XCD-L2-resident) ----------------
// chunk = blockIdx & 3 -> one 3.2MB h1c slice per XCD. Wave = 1 node.
// 2 lanes/edge (16B each), 32 edges per load instruction, fp16 packed accum.

union H8 { int4 i4; __half2 h2[4]; };

__device__ __forceinline__ __half2 shfl_xor_h2(__half2 a, int m) {
    int v = *(int*)&a;
    int s = __shfl_xor(v, m);
    return *(__half2*)&s;
}

__global__ __launch_bounds__(256) void g2c_k(
        const __half* __restrict__ h1c, const unsigned int* __restrict__ csr,
        const int* __restrict__ row_beg, const int* __restrict__ row_deg,
        __half* __restrict__ a2c) {
    __shared__ int sidx[4][64];          // per-wave index slice (wave-private)
    int wv = threadIdx.x >> 6;
    int c = blockIdx.x & 3;
    int nd = (blockIdx.x >> 2) * 4 + wv;
    int lane = threadIdx.x & 63;
    if (nd >= NN) return;
    const __half* hc = h1c + (size_t)c * NN * 16;
    int es = lane >> 1, p = lane & 1;    // edge slot 0..31, 16B half of the 32B chunk row
    int beg = row_beg[nd], deg = row_deg[nd];
    __half2 acc[4];
#pragma unroll
    for (int j = 0; j < 4; ++j) acc[j] = __half2half2(__float2half(0.f));
    int done = 0;
    while (done < deg) {
        int csz = deg - done;
        if (csz > 64) csz = 64;
        if (lane < csz) sidx[wv][lane] = (int)csr[beg + done + lane];  // 1 coalesced load
        int kb = 0;
        for (; kb + 31 < csz; kb += 32) {        // 32 edges: 1 x 16B load per lane
            int e0 = sidx[wv][kb + es];
            H8 r0;
            r0.i4 = *(const int4*)(hc + (size_t)e0 * 16 + p * 8);
#pragma unroll
            for (int j = 0; j < 4; ++j) acc[j] = __hadd2(acc[j], r0.h2[j]);
        }
        if (kb < csz) {                          // tail <32: predicated per lane-pair
            int ei = kb + es;
            if (ei < csz) {
                int e0 = sidx[wv][ei];
                H8 r0;
                r0.i4 = *(const int4*)(hc + (size_t)e0 * 16 + p * 8);
#pragma unroll
                for (int j = 0; j < 4; ++j) acc[j] = __hadd2(acc[j], r0.h2[j]);
            }
        }
        done += csz;
    }
    // reduce across 32 edge slots (keep p); uniform, all lanes active
#pragma unroll
    for (int j = 0; j < 4; ++j) {
        acc[j] = __hadd2(acc[j], shfl_xor_h2(acc[j], 2));
        acc[j] = __hadd2(acc[j], shfl_xor_h2(acc[j], 4));
        acc[j] = __hadd2(acc[j], shfl_xor_h2(acc[j], 8));
        acc[j] = __hadd2(acc[j], shfl_xor_h2(acc[j], 16));
        acc[j] = __hadd2(acc[j], shfl_xor_h2(acc[j], 32));
    }
    if (lane < 2) {                      // lanes 0,1 write the 32B chunk row
        H8 sv, o;
        sv.i4 = *(const int4*)(hc + (size_t)nd * 16 + p * 8);
#pragma unroll
        for (int j = 0; j < 4; ++j) o.h2[j] = __hadd2(acc[j], sv.h2[j]);
        *(int4*)(a2c + (size_t)c * NN * 16 + (size_t)nd * 16 + p * 8) = o.i4;
    }
}

// ---------------- combine2 + pool via MFMA: wave = 16 nodes, 8 mfma ----------------
// A from chunk-major a2c: k = kt*32+kb*8+j -> chunk cc = kt*2+(kb>>1), off (kb&1)*8.
// B from W2t[n][k]. C/D: col=lane&15 (n), row=(lane>>4)*4+reg (m).

__global__ __launch_bounds__(256) void c2mfma_k(
        const __half* __restrict__ a2c, const _Float16* __restrict__ W2t,
        const float* __restrict__ b2, const float* __restrict__ dinv,
        const int* __restrict__ batch, float* __restrict__ pool) {
    int tid = threadIdx.x;
    int wave = tid >> 6, lane = tid & 63;
    int base = blockIdx.x * 64 + wave * 16;
    int m = lane & 15, kb = lane >> 4;
    f16x8 bfr[2][4];
#pragma unroll
    for (int kt = 0; kt < 2; ++kt)
#pragma unroll
        for (int nt = 0; nt < 4; ++nt) {
            I4H8 u;
            u.i4 = *(const int4*)(W2t + (nt * 16 + m) * HD + kt * 32 + kb * 8);
            bfr[kt][nt] = u.h8;
        }
    f16x8 afr[2];
    int anode = base + m;
#pragma unroll
    for (int kt = 0; kt < 2; ++kt) {
        I4H8 u;
        int cc = kt * 2 + (kb >> 1);
        if (anode < NN)
            u.i4 = *(const int4*)(a2c + (size_t)cc * NN * 16 + (size_t)anode * 16 + (kb & 1) * 8);
        else
            u.i4 = make_int4(0, 0, 0, 0);
        afr[kt] = u.h8;
    }
    f32x4 acc[4] = {{0.f, 0.f, 0.f, 0.f}, {0.f, 0.f, 0.f, 0.f},
                    {0.f, 0.f, 0.f, 0.f}, {0.f, 0.f, 0.f, 0.f}};
#pragma unroll
    for (int kt = 0; kt < 2; ++kt)
#pragma unroll
        for (int nt = 0; nt < 4; ++nt)
            acc[nt] = __builtin_amdgcn_mfma_f32_16x16x32_f16(afr[kt], bfr[kt][nt], acc[nt], 0, 0, 0);
    int r0 = base + kb * 4;
    float dv[4];
    int bg[4];
#pragma unroll
    for (int r = 0; r < 4; ++r) {
        int node = r0 + r;
        dv[r] = (node < NN) ? dinv[node] : 0.f;
        bg[r] = (node < NN) ? batch[node] : -1;
    }
#pragma unroll
    for (int nt = 0; nt < 4; ++nt) {
        int n = nt * 16 + m;
        float bv = b2[n];
        int g = -1;
        float accf = 0.f;
#pragma unroll
        for (int r = 0; r < 4; ++r) {
            if (bg[r] < 0) break;
            float v = fmaxf(fmaf(dv[r], acc[nt][r], bv), 0.f);
            if (bg[r] != g) {
                if (g >= 0) atomicAdd(&pool[g * HD + n], accf);
                accf = 0.f; g = bg[r];
            }
            accf += v;
        }
        if (g >= 0) atomicAdd(&pool[g * HD + n], accf);
    }
}

__device__ __forceinline__ int lb_dev(const int* __restrict__ b, int n, int key) {
    int lo = 0, hi = n;
    while (lo < hi) {
        int mid = (lo + hi) >> 1;
        if (b[mid] < key) lo = mid + 1; else hi = mid;
    }
    return lo;
}

__global__ void final_k(const float* __restrict__ pool, const int* __restrict__ batch,
                        const float* __restrict__ Wlin, const float* __restrict__ blin,
                        float* __restrict__ out) {
    int g = blockIdx.x;
    int lane = threadIdx.x;
    int lo = lb_dev(batch, NN, g);
    int hi = lb_dev(batch, NN, g + 1);
    float cnt = (float)(hi - lo);
    float v = pool[g * HD + lane] * Wlin[lane];
#pragma unroll
    for (int off = 32; off > 0; off >>= 1) v += __shfl_down(v, off);
    if (lane == 0) out[g] = v / fmaxf(cnt, 1.0f) + blin[0];
}

// ---------------- launch ----------------

extern "C" void kernel_launch(void* const* d_in, const int* in_sizes, int n_in,
                              void* d_out, int out_size, void* d_ws, size_t ws_size,
                              hipStream_t stream) {
    const float* x    = (const float*)d_in[0];
    const int*   ei   = (const int*)d_in[1];
    const int*   bat  = (const int*)d_in[2];
    const float* W1   = (const float*)d_in[3];
    const float* b1   = (const float*)d_in[4];
    const float* W2   = (const float*)d_in[5];
    const float* b2   = (const float*)d_in[6];
    const float* Wlin = (const float*)d_in[7];
    const float* blin = (const float*)d_in[8];
    float* out = (float*)d_out;

    const int* src = ei;
    const int* dst = ei + NE;

    char* ws = (char*)d_ws;
    size_t off = 0;
    auto alloc = [&](size_t bytes) {
        char* p = ws + off;
        off += (bytes + 255) & ~(size_t)255;
        return p;
    };
    int*   bcur    = (int*)  alloc((NBUK + 1) * sizeof(int));
    int*   row_beg = (int*)  alloc(NN * sizeof(int));
    int*   row_deg = (int*)  alloc(NN * sizeof(int));
    float* dinv    = (float*)alloc(NN * sizeof(float));
    unsigned int* edges2 = (unsigned int*)alloc((size_t)NBUK * CAP * sizeof(unsigned int)); // 14.4 MB
    float4* xs     = (float4*)alloc((size_t)NN * sizeof(float4));
    __half* h1c    = (__half*)alloc((size_t)NN * HD * sizeof(__half));
    __half* a2c    = (__half*)alloc((size_t)NN * HD * sizeof(__half));
    _Float16* W2t  = (_Float16*)alloc(HD * HD * sizeof(_Float16));
    float* pool    = (float*)alloc((size_t)NG * HD * sizeof(float));
    (void)ws_size; (void)n_in; (void)in_sizes; (void)out_size;

    const int BLK = 256;
    const int gW = (NN * 64 + BLK - 1) / BLK;   // one wave per node

    // build: bucket runs -> in-place fine sort (+ W2 transpose/convert)
    init_k<<<(NBUK + 1 + 255) / 256, 256, 0, stream>>>(bcur);
    w2t_k<<<16, 256, 0, stream>>>(W2, W2t);
    stageA_k<<<NB, 512, 0, stream>>>(src, dst, bcur, edges2);
    build1_k<<<NBUK, 512, 0, stream>>>(bcur, (const float4*)x, edges2,
                                       row_beg, row_deg, dinv, xs);

    // layer 1 fused: gather + W1 GEMM -> fp16 h1 (chunk-major)
    g1f_k<<<gW, BLK, 0, stream>>>(xs, edges2, row_beg, row_deg, dinv, W1, b1, h1c);

    // layer 2: chunk-partitioned gather (4 chunks, XCD-L2-resident) -> fp16 a2 (chunk-major)
    g2c_k<<<((NN + 3) / 4) * 4, BLK, 0, stream>>>(h1c, edges2, row_beg, row_deg, a2c);

    // combine + pool + readout (MFMA GEMM, 64 nodes per block)
    hipMemsetAsync(pool, 0, (size_t)NG * HD * sizeof(float), stream);
    c2mfma_k<<<(NN + 63) / 64, 256, 0, stream>>>(a2c, W2t, b2, dinv, bat, pool);
    final_k<<<NG, 64, 0, stream>>>(pool, bat, Wlin, blin, out);
}

// Round 21
// 173.206 us; speedup vs baseline: 1.4258x; 1.4258x over previous
//
#include <hip/hip_runtime.h>
#include <hip/hip_fp16.h>

#define NN 100000
#define NE 3200000
#define NG 2048
#define HD 64
#define BUKSZ 256         // nodes per bucket
#define NBUK 391          // ceil(NN / BUKSZ)
#define NB 512            // stage blocks
#define CHUNK 6250        // NE / NB exactly
#define CAP 9216          // padded edge capacity per bucket

// NOTE: int LDS atomics only. Float LDS atomicAdd is a CAS loop (R8: 1342us).
// NOTE2 (R9): latency-bound gathers want max independent waves.
// NOTE3 (R11): shfl with divergent srcLane under divergent bounds is undefined.
//   All-lanes-active uniform shfl (__shfl_up with constant delta) is safe.
// NOTE4 (R15): 16B/lane loads: 4 rows per VMEM instr.
// NOTE5 (R16): >16-float per-thread arrays spill to scratch (205MB = 60us).
// NOTE6 (R17): readlane-GEMM is VALU-issue-bound; MFMA = 8 ops/wave (R18: -28us).
// NOTE7 (R19): packed fp16 accumulation removes cvt from gather inner loop.
// NOTE8 (R20): chunk-per-XCD gather fixed FETCH (158->50MB) but 4x per-node
// overhead (stage+reduce per chunk) made it 2.4x slower. Gather is pinned at
// ~54us by L2 replication; row-major R19 form is the keeper.

typedef __attribute__((ext_vector_type(8))) _Float16 f16x8;
typedef __attribute__((ext_vector_type(4))) float f32x4;
union I4H8 { int4 i4; f16x8 h8; };

// ---------------- setup: bucket cursors + W2 transpose/convert (merged) ----------------

__global__ void setup_k(int* __restrict__ bcur, const float* __restrict__ W2,
                        _Float16* __restrict__ W2t) {
    int t = blockIdx.x * blockDim.x + threadIdx.x;
    if (t < HD * HD) {
        int n = t >> 6, k = t & 63;
        W2t[n * HD + k] = (_Float16)W2[k * HD + n];
    }
    int u = t - HD * HD;
    if (u >= 0 && u <= NBUK) bcur[u] = u * CAP;
}

// ---------------- pass 1: block-local bucket sort -> padded bucket runs ----------------
// packed value: (dst & 255) << 17 | src   (src < 2^17)
// scan: per-wave shfl_up inclusive scan + single-thread wave-sum combine (2 barriers)

__global__ __launch_bounds__(512) void stageA_k(
        const int* __restrict__ src, const int* __restrict__ dst,
        int* __restrict__ bcur, unsigned int* __restrict__ edges2) {
    __shared__ int hist[NBUK];
    __shared__ int exb[NBUK + 1];
    __shared__ int cur[NBUK];
    __shared__ int obase[NBUK];
    __shared__ int wsum[8];
    __shared__ int wpre[8];
    __shared__ unsigned int svals[CHUNK];
    __shared__ unsigned short sbuk[CHUNK];   // bucket id per sorted slot
    int b = blockIdx.x, t = threadIdx.x;
    int lane = t & 63, wv = t >> 6;
    int base = b * CHUNK;
    for (int i = t; i < NBUK; i += 512) hist[i] = 0;
    __syncthreads();
    for (int i = t; i < CHUNK; i += 512)
        atomicAdd(&hist[dst[base + i] >> 8], 1);
    __syncthreads();
    int v = (t < NBUK) ? hist[t] : 0;
    // wave-level inclusive scan (all lanes active, uniform shfl)
    int x = v;
#pragma unroll
    for (int o = 1; o < 64; o <<= 1) {
        int y = __shfl_up(x, o);
        if (lane >= o) x += y;
    }
    if (lane == 63) wsum[wv] = x;
    __syncthreads();
    if (t == 0) {
        int s = 0;
#pragma unroll
        for (int i = 0; i < 8; ++i) { wpre[i] = s; s += wsum[i]; }
    }
    __syncthreads();
    int excl = x - v + wpre[wv];
    if (t < NBUK) {
        exb[t] = excl;
        cur[t] = excl;
        obase[t] = v ? atomicAdd(&bcur[t], v) : 0;
    }
    if (t == 0) exb[NBUK] = CHUNK;
    __syncthreads();
    for (int i = t; i < CHUNK; i += 512) {
        int d = dst[base + i];
        int s = src[base + i];
        int bk = d >> 8;
        int pos = atomicAdd(&cur[bk], 1);
        svals[pos] = ((unsigned int)(d & 255) << 17) | (unsigned int)s;
        sbuk[pos] = (unsigned short)bk;
    }
    __syncthreads();
    for (int i = t; i < CHUNK; i += 512) {
        int lo = (int)sbuk[i];
        edges2[obase[lo] + (i - exb[lo])] = svals[i];
    }
}

// ---------------- pass 2: per-bucket fine sort (in-place) + row info + dinv + xs ----------------

__global__ __launch_bounds__(512) void build1_k(
        const int* __restrict__ bcur, const float4* __restrict__ x,
        unsigned int* __restrict__ edges2, int* __restrict__ row_beg,
        int* __restrict__ row_deg, float* __restrict__ dinv,
        float4* __restrict__ xs) {
    __shared__ unsigned int ebuf[CAP];   // 36 KB
    __shared__ int deg[BUKSZ];
    __shared__ int sc[BUKSZ];
    __shared__ int cur[BUKSZ];
    int k = blockIdx.x, t = threadIdx.x;
    int base = k * CAP;
    int len = bcur[k] - base;
    if (t < BUKSZ) deg[t] = 0;
    __syncthreads();
    for (int i = t; i < len; i += 512) {
        unsigned int pv = edges2[base + i];
        ebuf[i] = pv;
        atomicAdd(&deg[pv >> 17], 1);
    }
    __syncthreads();
    int v = 0;
    if (t < BUKSZ) { v = deg[t]; sc[t] = v; }
    __syncthreads();
    for (int o = 1; o < BUKSZ; o <<= 1) {
        int u = 0;
        if (t < BUKSZ && t >= o) u = sc[t - o];
        __syncthreads();
        if (t < BUKSZ && t >= o) sc[t] += u;
        __syncthreads();
    }
    if (t < BUKSZ) {
        int excl = sc[t] - v;
        cur[t] = excl;
        int node = k * BUKSZ + t;
        if (node < NN) {
            row_beg[node] = base + excl;
            row_deg[node] = v;
            float di = rsqrtf((float)v + 1.0f);
            dinv[node] = di;
            float4 xv = x[node];
            xs[node] = make_float4(xv.x * di, xv.y * di, xv.z * di, xv.w * di);
        }
    }
    __syncthreads();
    for (int i = t; i < len; i += 512) {
        unsigned int pv = ebuf[i];
        int pos = atomicAdd(&cur[pv >> 17], 1);
        edges2[base + pos] = pv & 0x1FFFFu;
    }
}

// ---------------- layer 1 FUSED: wave-per-node gather + W1 GEMM -> fp16 h1 ----------------

__global__ __launch_bounds__(256) void g1f_k(
        const float4* __restrict__ xs, const unsigned int* __restrict__ csr,
        const int* __restrict__ row_beg, const int* __restrict__ row_deg,
        const float* __restrict__ dinv, const float* __restrict__ W1,
        const float* __restrict__ b1, __half* __restrict__ h1) {
    int wid = (blockIdx.x * blockDim.x + threadIdx.x) >> 6;
    int lane = threadIdx.x & 63;
    if (wid >= NN) return;
    int beg = row_beg[wid], deg = row_deg[wid];
    float sx = 0.f, sy = 0.f, sz = 0.f, sw = 0.f;
    for (int e = beg + lane; e < beg + deg; e += 64) {
        float4 w = xs[csr[e]];
        sx += w.x; sy += w.y; sz += w.z; sw += w.w;
    }
#pragma unroll
    for (int o = 1; o < 64; o <<= 1) {
        sx += __shfl_xor(sx, o);
        sy += __shfl_xor(sy, o);
        sz += __shfl_xor(sz, o);
        sw += __shfl_xor(sw, o);
    }
    float di = dinv[wid];
    float4 self = xs[wid];
    float ax = (sx + self.x) * di;
    float ay = (sy + self.y) * di;
    float az = (sz + self.z) * di;
    float aw = (sw + self.w) * di;
    float v = ax * W1[lane] + ay * W1[64 + lane] + az * W1[128 + lane] + aw * W1[192 + lane] + b1[lane];
    v = fmaxf(v, 0.f) * di;
    h1[(size_t)wid * HD + lane] = __float2half_rn(v);
}

// ---------------- layer 2 gather: wave per node; 16B/lane loads, fp16 packed accum ----------------

union H8 { int4 i4; __half2 h2[4]; };

__device__ __forceinline__ __half2 shfl_xor_h2(__half2 a, int m) {
    int v = *(int*)&a;
    int s = __shfl_xor(v, m);
    return *(__half2*)&s;
}

__global__ __launch_bounds__(256) void gather2_k(
        const __half* __restrict__ h1, const unsigned int* __restrict__ csr,
        const int* __restrict__ row_beg, const int* __restrict__ row_deg,
        __half* __restrict__ a2h) {
    __shared__ int sidx[4][64];          // per-wave index slice (wave-private)
    int wv = threadIdx.x >> 6;
    int wid = (blockIdx.x * blockDim.x + threadIdx.x) >> 6;
    int lane = threadIdx.x & 63;
    if (wid >= NN) return;
    int half = lane >> 5;
    int g = (lane >> 3) & 3;
    int sub = lane & 7;
    int hg = half * 4 + g;               // edge slot 0..7 within an 8-edge block
    int beg = row_beg[wid], deg = row_deg[wid];
    __half2 acc[4];
#pragma unroll
    for (int j = 0; j < 4; ++j) acc[j] = __half2half2(__float2half(0.f));
    int done = 0;
    while (done < deg) {
        int chunk = deg - done;
        if (chunk > 64) chunk = 64;
        if (lane < chunk) sidx[wv][lane] = (int)csr[beg + done + lane];  // 1 coalesced load
        int kb = 0;
        for (; kb + 31 < chunk; kb += 32) {      // 32 edges: 4 x 16B loads/lane
            int e0 = sidx[wv][kb + hg];
            int e1 = sidx[wv][kb + hg + 8];
            int e2 = sidx[wv][kb + hg + 16];
            int e3 = sidx[wv][kb + hg + 24];
            H8 r0, r1, r2, r3;
            r0.i4 = *(const int4*)(h1 + (size_t)e0 * HD + sub * 8);
            r1.i4 = *(const int4*)(h1 + (size_t)e1 * HD + sub * 8);
            r2.i4 = *(const int4*)(h1 + (size_t)e2 * HD + sub * 8);
            r3.i4 = *(const int4*)(h1 + (size_t)e3 * HD + sub * 8);
#pragma unroll
            for (int j = 0; j < 4; ++j) {
                acc[j] = __hadd2(acc[j], __hadd2(__hadd2(r0.h2[j], r1.h2[j]),
                                                 __hadd2(r2.h2[j], r3.h2[j])));
            }
        }
        for (; kb + 7 < chunk; kb += 8) {        // 8 edges: 1 load/lane
            int e0 = sidx[wv][kb + hg];
            H8 r0;
            r0.i4 = *(const int4*)(h1 + (size_t)e0 * HD + sub * 8);
#pragma unroll
            for (int j = 0; j < 4; ++j) acc[j] = __hadd2(acc[j], r0.h2[j]);
        }
        if (kb < chunk) {                        // tail <8: predicated per 8-lane group
            int e = kb + hg;
            if (e < chunk) {
                int e0 = sidx[wv][e];
                H8 r0;
                r0.i4 = *(const int4*)(h1 + (size_t)e0 * HD + sub * 8);
#pragma unroll
                for (int j = 0; j < 4; ++j) acc[j] = __hadd2(acc[j], r0.h2[j]);
            }
        }
        done += chunk;
    }
    // reduce across groups (xor 8,16) and halves (xor 32); uniform, all lanes active
#pragma unroll
    for (int j = 0; j < 4; ++j) {
        acc[j] = __hadd2(acc[j], shfl_xor_h2(acc[j], 8));
        acc[j] = __hadd2(acc[j], shfl_xor_h2(acc[j], 16));
        acc[j] = __hadd2(acc[j], shfl_xor_h2(acc[j], 32));
    }
    if (half == 0 && g == 0) {               // 8 lanes write the 128B row
        H8 sv, o;
        sv.i4 = *(const int4*)(h1 + (size_t)wid * HD + sub * 8);
#pragma unroll
        for (int j = 0; j < 4; ++j) o.h2[j] = __hadd2(acc[j], sv.h2[j]);
        ((int4*)a2h)[(size_t)wid * 8 + sub] = o.i4;
    }
}

// ---------------- combine2 + pool via MFMA: wave = 16 nodes, 8 mfma ----------------
// D[m][n] = sum_k a2[base+m][k] * W2[k][n]; A lane: m=lane&15, k=(lane>>4)*8+j.
// B from W2t[n][k]: n=lane&15, same k mapping. C/D: col=lane&15, row=(lane>>4)*4+reg.

__global__ __launch_bounds__(256) void c2mfma_k(
        const __half* __restrict__ a2h, const _Float16* __restrict__ W2t,
        const float* __restrict__ b2, const float* __restrict__ dinv,
        const int* __restrict__ batch, float* __restrict__ pool) {
    int tid = threadIdx.x;
    int wave = tid >> 6, lane = tid & 63;
    int base = blockIdx.x * 64 + wave * 16;
    int m = lane & 15, kb = lane >> 4;
    f16x8 bfr[2][4];
#pragma unroll
    for (int kt = 0; kt < 2; ++kt)
#pragma unroll
        for (int nt = 0; nt < 4; ++nt) {
            I4H8 u;
            u.i4 = *(const int4*)(W2t + (nt * 16 + m) * HD + kt * 32 + kb * 8);
            bfr[kt][nt] = u.h8;
        }
    f16x8 afr[2];
    int anode = base + m;
#pragma unroll
    for (int kt = 0; kt < 2; ++kt) {
        I4H8 u;
        if (anode < NN)
            u.i4 = *(const int4*)(a2h + (size_t)anode * HD + kt * 32 + kb * 8);
        else
            u.i4 = make_int4(0, 0, 0, 0);
        afr[kt] = u.h8;
    }
    f32x4 acc[4] = {{0.f, 0.f, 0.f, 0.f}, {0.f, 0.f, 0.f, 0.f},
                    {0.f, 0.f, 0.f, 0.f}, {0.f, 0.f, 0.f, 0.f}};
#pragma unroll
    for (int kt = 0; kt < 2; ++kt)
#pragma unroll
        for (int nt = 0; nt < 4; ++nt)
            acc[nt] = __builtin_amdgcn_mfma_f32_16x16x32_f16(afr[kt], bfr[kt][nt], acc[nt], 0, 0, 0);
    int r0 = base + kb * 4;
    float dv[4];
    int bg[4];
#pragma unroll
    for (int r = 0; r < 4; ++r) {
        int node = r0 + r;
        dv[r] = (node < NN) ? dinv[node] : 0.f;
        bg[r] = (node < NN) ? batch[node] : -1;
    }
#pragma unroll
    for (int nt = 0; nt < 4; ++nt) {
        int n = nt * 16 + m;
        float bv = b2[n];
        int g = -1;
        float accf = 0.f;
#pragma unroll
        for (int r = 0; r < 4; ++r) {
            if (bg[r] < 0) break;
            float v = fmaxf(fmaf(dv[r], acc[nt][r], bv), 0.f);
            if (bg[r] != g) {
                if (g >= 0) atomicAdd(&pool[g * HD + n], accf);
                accf = 0.f; g = bg[r];
            }
            accf += v;
        }
        if (g >= 0) atomicAdd(&pool[g * HD + n], accf);
    }
}

__device__ __forceinline__ int lb_dev(const int* __restrict__ b, int n, int key) {
    int lo = 0, hi = n;
    while (lo < hi) {
        int mid = (lo + hi) >> 1;
        if (b[mid] < key) lo = mid + 1; else hi = mid;
    }
    return lo;
}

__global__ void final_k(const float* __restrict__ pool, const int* __restrict__ batch,
                        const float* __restrict__ Wlin, const float* __restrict__ blin,
                        float* __restrict__ out) {
    int g = blockIdx.x;
    int lane = threadIdx.x;
    int lo = lb_dev(batch, NN, g);
    int hi = lb_dev(batch, NN, g + 1);
    float cnt = (float)(hi - lo);
    float v = pool[g * HD + lane] * Wlin[lane];
#pragma unroll
    for (int off = 32; off > 0; off >>= 1) v += __shfl_down(v, off);
    if (lane == 0) out[g] = v / fmaxf(cnt, 1.0f) + blin[0];
}

// ---------------- launch ----------------

extern "C" void kernel_launch(void* const* d_in, const int* in_sizes, int n_in,
                              void* d_out, int out_size, void* d_ws, size_t ws_size,
                              hipStream_t stream) {
    const float* x    = (const float*)d_in[0];
    const int*   ei   = (const int*)d_in[1];
    const int*   bat  = (const int*)d_in[2];
    const float* W1   = (const float*)d_in[3];
    const float* b1   = (const float*)d_in[4];
    const float* W2   = (const float*)d_in[5];
    const float* b2   = (const float*)d_in[6];
    const float* Wlin = (const float*)d_in[7];
    const float* blin = (const float*)d_in[8];
    float* out = (float*)d_out;

    const int* src = ei;
    const int* dst = ei + NE;

    char* ws = (char*)d_ws;
    size_t off = 0;
    auto alloc = [&](size_t bytes) {
        char* p = ws + off;
        off += (bytes + 255) & ~(size_t)255;
        return p;
    };
    int*   bcur    = (int*)  alloc((NBUK + 1) * sizeof(int));
    int*   row_beg = (int*)  alloc(NN * sizeof(int));
    int*   row_deg = (int*)  alloc(NN * sizeof(int));
    float* dinv    = (float*)alloc(NN * sizeof(float));
    unsigned int* edges2 = (unsigned int*)alloc((size_t)NBUK * CAP * sizeof(unsigned int)); // 14.4 MB
    float4* xs     = (float4*)alloc((size_t)NN * sizeof(float4));
    __half* h1     = (__half*)alloc((size_t)NN * HD * sizeof(__half));
    __half* a2h    = (__half*)alloc((size_t)NN * HD * sizeof(__half));
    _Float16* W2t  = (_Float16*)alloc(HD * HD * sizeof(_Float16));
    float* pool    = (float*)alloc((size_t)NG * HD * sizeof(float));
    (void)ws_size; (void)n_in; (void)in_sizes; (void)out_size;

    const int BLK = 256;
    const int gW = (NN * 64 + BLK - 1) / BLK;   // one wave per node

    // setup (cursors + W2t) -> bucket runs -> in-place fine sort
    setup_k<<<(HD * HD + NBUK + 1 + 255) / 256, 256, 0, stream>>>(bcur, W2, W2t);
    stageA_k<<<NB, 512, 0, stream>>>(src, dst, bcur, edges2);
    build1_k<<<NBUK, 512, 0, stream>>>(bcur, (const float4*)x, edges2,
                                       row_beg, row_deg, dinv, xs);

    // layer 1 fused: gather + W1 GEMM -> fp16 h1
    g1f_k<<<gW, BLK, 0, stream>>>(xs, edges2, row_beg, row_deg, dinv, W1, b1, h1);

    // layer 2: wide-load gather, fp16 packed accumulation -> fp16 a2
    gather2_k<<<gW, BLK, 0, stream>>>(h1, edges2, row_beg, row_deg, a2h);

    // combine + pool + readout (MFMA GEMM, 64 nodes per block)
    hipMemsetAsync(pool, 0, (size_t)NG * HD * sizeof(float), stream);
    c2mfma_k<<<(NN + 63) / 64, 256, 0, stream>>>(a2h, W2t, b2, dinv, bat, pool);
    final_k<<<NG, 64, 0, stream>>>(pool, bat, Wlin, blin, out);
}

// Round 22
// 172.400 us; speedup vs baseline: 1.4325x; 1.0047x over previous
//
#include <hip/hip_runtime.h>
#include <hip/hip_fp16.h>

#define NN 100000
#define NE 3200000
#define NG 2048
#define HD 64
#define BUKSZ 256         // nodes per bucket
#define NBUK 391          // ceil(NN / BUKSZ)
#define NB 512            // stage blocks
#define CHUNK 6250        // NE / NB exactly
#define CAP 9216          // padded edge capacity per bucket

// NOTE: int LDS atomics only. Float LDS atomicAdd is a CAS loop (R8: 1342us).
// NOTE2 (R9): latency-bound gathers want max independent waves.
// NOTE3 (R11): shfl with divergent srcLane under divergent bounds is undefined.
//   All-lanes-active uniform shfl (__shfl_up/xor, const operand) is safe.
// NOTE4 (R15): 16B/lane loads: 4 rows per VMEM instr.
// NOTE5 (R16): >16-float per-thread arrays spill to scratch (205MB = 60us).
// NOTE6 (R17): readlane-GEMM is VALU-issue-bound; MFMA = 8 ops/wave (R18: -28us).
// NOTE7 (R19): packed fp16 accumulation removes cvt from gather inner loop.
// NOTE8 (R20): chunk-per-XCD gather fixed FETCH (158->50MB) but 4x per-node
// overhead made it 2.4x slower. Gather pinned ~54us by 8-XCD L2 replication
// (mandatory 102MB refetch of the 12.8MB h1); floor ~35-40us, escapes cost more.

typedef __attribute__((ext_vector_type(8))) _Float16 f16x8;
typedef __attribute__((ext_vector_type(4))) float f32x4;
union I4H8 { int4 i4; f16x8 h8; };

// ---------------- setup: bucket cursors + W2 transpose/convert + pool zero ----------------

__global__ void setup_k(int* __restrict__ bcur, const float* __restrict__ W2,
                        _Float16* __restrict__ W2t, float* __restrict__ pool) {
    int t = blockIdx.x * blockDim.x + threadIdx.x;
    if (t < NG * HD) pool[t] = 0.f;
    if (t < HD * HD) {
        int n = t >> 6, k = t & 63;
        W2t[n * HD + k] = (_Float16)W2[k * HD + n];
    }
    if (t <= NBUK) bcur[t] = t * CAP;
}

// ---------------- pass 1: block-local bucket sort -> padded bucket runs ----------------
// packed value: (dst & 255) << 17 | src   (src < 2^17)
// scan: per-wave shfl_up inclusive scan + single-thread wave-sum combine (2 barriers)

__global__ __launch_bounds__(512) void stageA_k(
        const int* __restrict__ src, const int* __restrict__ dst,
        int* __restrict__ bcur, unsigned int* __restrict__ edges2) {
    __shared__ int hist[NBUK];
    __shared__ int exb[NBUK + 1];
    __shared__ int cur[NBUK];
    __shared__ int obase[NBUK];
    __shared__ int wsum[8];
    __shared__ int wpre[8];
    __shared__ unsigned int svals[CHUNK];
    __shared__ unsigned short sbuk[CHUNK];   // bucket id per sorted slot
    int b = blockIdx.x, t = threadIdx.x;
    int lane = t & 63, wv = t >> 6;
    int base = b * CHUNK;
    for (int i = t; i < NBUK; i += 512) hist[i] = 0;
    __syncthreads();
    for (int i = t; i < CHUNK; i += 512)
        atomicAdd(&hist[dst[base + i] >> 8], 1);
    __syncthreads();
    int v = (t < NBUK) ? hist[t] : 0;
    int x = v;
#pragma unroll
    for (int o = 1; o < 64; o <<= 1) {
        int y = __shfl_up(x, o);
        if (lane >= o) x += y;
    }
    if (lane == 63) wsum[wv] = x;
    __syncthreads();
    if (t == 0) {
        int s = 0;
#pragma unroll
        for (int i = 0; i < 8; ++i) { wpre[i] = s; s += wsum[i]; }
    }
    __syncthreads();
    int excl = x - v + wpre[wv];
    if (t < NBUK) {
        exb[t] = excl;
        cur[t] = excl;
        obase[t] = v ? atomicAdd(&bcur[t], v) : 0;
    }
    if (t == 0) exb[NBUK] = CHUNK;
    __syncthreads();
    for (int i = t; i < CHUNK; i += 512) {
        int d = dst[base + i];
        int s = src[base + i];
        int bk = d >> 8;
        int pos = atomicAdd(&cur[bk], 1);
        svals[pos] = ((unsigned int)(d & 255) << 17) | (unsigned int)s;
        sbuk[pos] = (unsigned short)bk;
    }
    __syncthreads();
    for (int i = t; i < CHUNK; i += 512) {
        int lo = (int)sbuk[i];
        edges2[obase[lo] + (i - exb[lo])] = svals[i];
    }
}

// ---------------- pass 2: per-bucket fine sort (in-place) + row info + dinv + xs ----------------
// scan over 256 degs: wave shfl_up scan (waves 0-3) + combine (2 barriers)

__global__ __launch_bounds__(512) void build1_k(
        const int* __restrict__ bcur, const float4* __restrict__ x,
        unsigned int* __restrict__ edges2, int* __restrict__ row_beg,
        int* __restrict__ row_deg, float* __restrict__ dinv,
        float4* __restrict__ xs) {
    __shared__ unsigned int ebuf[CAP];   // 36 KB
    __shared__ int deg[BUKSZ];
    __shared__ int cur[BUKSZ];
    __shared__ int wsum[8];
    __shared__ int wpre[8];
    int k = blockIdx.x, t = threadIdx.x;
    int lane = t & 63, wv = t >> 6;
    int base = k * CAP;
    int len = bcur[k] - base;
    if (t < BUKSZ) deg[t] = 0;
    __syncthreads();
    for (int i = t; i < len; i += 512) {
        unsigned int pv = edges2[base + i];
        ebuf[i] = pv;
        atomicAdd(&deg[pv >> 17], 1);
    }
    __syncthreads();
    int v = (t < BUKSZ) ? deg[t] : 0;
    int xsc = v;
#pragma unroll
    for (int o = 1; o < 64; o <<= 1) {
        int y = __shfl_up(xsc, o);
        if (lane >= o) xsc += y;
    }
    if (lane == 63) wsum[wv] = xsc;
    __syncthreads();
    if (t == 0) {
        int s = 0;
#pragma unroll
        for (int i = 0; i < 8; ++i) { wpre[i] = s; s += wsum[i]; }
    }
    __syncthreads();
    if (t < BUKSZ) {
        int excl = xsc - v + wpre[wv];
        cur[t] = excl;
        int node = k * BUKSZ + t;
        if (node < NN) {
            row_beg[node] = base + excl;
            row_deg[node] = v;
            float di = rsqrtf((float)v + 1.0f);
            dinv[node] = di;
            float4 xv = x[node];
            xs[node] = make_float4(xv.x * di, xv.y * di, xv.z * di, xv.w * di);
        }
    }
    __syncthreads();
    for (int i = t; i < len; i += 512) {
        unsigned int pv = ebuf[i];
        int pos = atomicAdd(&cur[pv >> 17], 1);
        edges2[base + pos] = pv & 0x1FFFFu;
    }
}

// ---------------- layer 1 FUSED: wave-per-node gather + W1 GEMM -> fp16 h1 ----------------

__global__ __launch_bounds__(256) void g1f_k(
        const float4* __restrict__ xs, const unsigned int* __restrict__ csr,
        const int* __restrict__ row_beg, const int* __restrict__ row_deg,
        const float* __restrict__ dinv, const float* __restrict__ W1,
        const float* __restrict__ b1, __half* __restrict__ h1) {
    int wid = (blockIdx.x * blockDim.x + threadIdx.x) >> 6;
    int lane = threadIdx.x & 63;
    if (wid >= NN) return;
    int beg = row_beg[wid], deg = row_deg[wid];
    float sx = 0.f, sy = 0.f, sz = 0.f, sw = 0.f;
    for (int e = beg + lane; e < beg + deg; e += 64) {
        float4 w = xs[csr[e]];
        sx += w.x; sy += w.y; sz += w.z; sw += w.w;
    }
#pragma unroll
    for (int o = 1; o < 64; o <<= 1) {
        sx += __shfl_xor(sx, o);
        sy += __shfl_xor(sy, o);
        sz += __shfl_xor(sz, o);
        sw += __shfl_xor(sw, o);
    }
    float di = dinv[wid];
    float4 self = xs[wid];
    float ax = (sx + self.x) * di;
    float ay = (sy + self.y) * di;
    float az = (sz + self.z) * di;
    float aw = (sw + self.w) * di;
    float v = ax * W1[lane] + ay * W1[64 + lane] + az * W1[128 + lane] + aw * W1[192 + lane] + b1[lane];
    v = fmaxf(v, 0.f) * di;
    h1[(size_t)wid * HD + lane] = __float2half_rn(v);
}

// ---------------- layer 2 gather: wave per node; 16B/lane loads, fp16 packed accum ----------------

union H8 { int4 i4; __half2 h2[4]; };

__device__ __forceinline__ __half2 shfl_xor_h2(__half2 a, int m) {
    int v = *(int*)&a;
    int s = __shfl_xor(v, m);
    return *(__half2*)&s;
}

__global__ __launch_bounds__(512) void gather2_k(
        const __half* __restrict__ h1, const unsigned int* __restrict__ csr,
        const int* __restrict__ row_beg, const int* __restrict__ row_deg,
        __half* __restrict__ a2h) {
    __shared__ int sidx[8][64];          // per-wave index slice (wave-private)
    int wv = threadIdx.x >> 6;
    int wid = (blockIdx.x * blockDim.x + threadIdx.x) >> 6;
    int lane = threadIdx.x & 63;
    if (wid >= NN) return;
    int half = lane >> 5;
    int g = (lane >> 3) & 3;
    int sub = lane & 7;
    int hg = half * 4 + g;               // edge slot 0..7 within an 8-edge block
    int beg = row_beg[wid], deg = row_deg[wid];
    __half2 acc[4];
#pragma unroll
    for (int j = 0; j < 4; ++j) acc[j] = __half2half2(__float2half(0.f));
    int done = 0;
    while (done < deg) {
        int chunk = deg - done;
        if (chunk > 64) chunk = 64;
        if (lane < chunk) sidx[wv][lane] = (int)csr[beg + done + lane];  // 1 coalesced load
        int kb = 0;
        for (; kb + 31 < chunk; kb += 32) {      // 32 edges: 4 x 16B loads/lane
            int e0 = sidx[wv][kb + hg];
            int e1 = sidx[wv][kb + hg + 8];
            int e2 = sidx[wv][kb + hg + 16];
            int e3 = sidx[wv][kb + hg + 24];
            H8 r0, r1, r2, r3;
            r0.i4 = *(const int4*)(h1 + (size_t)e0 * HD + sub * 8);
            r1.i4 = *(const int4*)(h1 + (size_t)e1 * HD + sub * 8);
            r2.i4 = *(const int4*)(h1 + (size_t)e2 * HD + sub * 8);
            r3.i4 = *(const int4*)(h1 + (size_t)e3 * HD + sub * 8);
#pragma unroll
            for (int j = 0; j < 4; ++j) {
                acc[j] = __hadd2(acc[j], __hadd2(__hadd2(r0.h2[j], r1.h2[j]),
                                                 __hadd2(r2.h2[j], r3.h2[j])));
            }
        }
        for (; kb + 7 < chunk; kb += 8) {        // 8 edges: 1 load/lane
            int e0 = sidx[wv][kb + hg];
            H8 r0;
            r0.i4 = *(const int4*)(h1 + (size_t)e0 * HD + sub * 8);
#pragma unroll
            for (int j = 0; j < 4; ++j) acc[j] = __hadd2(acc[j], r0.h2[j]);
        }
        if (kb < chunk) {                        // tail <8: predicated per 8-lane group
            int e = kb + hg;
            if (e < chunk) {
                int e0 = sidx[wv][e];
                H8 r0;
                r0.i4 = *(const int4*)(h1 + (size_t)e0 * HD + sub * 8);
#pragma unroll
                for (int j = 0; j < 4; ++j) acc[j] = __hadd2(acc[j], r0.h2[j]);
            }
        }
        done += chunk;
    }
    // reduce across groups (xor 8,16) and halves (xor 32); uniform, all lanes active
#pragma unroll
    for (int j = 0; j < 4; ++j) {
        acc[j] = __hadd2(acc[j], shfl_xor_h2(acc[j], 8));
        acc[j] = __hadd2(acc[j], shfl_xor_h2(acc[j], 16));
        acc[j] = __hadd2(acc[j], shfl_xor_h2(acc[j], 32));
    }
    if (half == 0 && g == 0) {               // 8 lanes write the 128B row
        H8 sv, o;
        sv.i4 = *(const int4*)(h1 + (size_t)wid * HD + sub * 8);
#pragma unroll
        for (int j = 0; j < 4; ++j) o.h2[j] = __hadd2(acc[j], sv.h2[j]);
        ((int4*)a2h)[(size_t)wid * 8 + sub] = o.i4;
    }
}

// ---------------- combine2 + pool via MFMA: wave = 16 nodes, 8 mfma ----------------
// D[m][n] = sum_k a2[base+m][k] * W2[k][n]; A lane: m=lane&15, k=(lane>>4)*8+j.
// B from W2t[n][k]: n=lane&15, same k mapping. C/D: col=lane&15, row=(lane>>4)*4+reg.

__global__ __launch_bounds__(256) void c2mfma_k(
        const __half* __restrict__ a2h, const _Float16* __restrict__ W2t,
        const float* __restrict__ b2, const float* __restrict__ dinv,
        const int* __restrict__ batch, float* __restrict__ pool) {
    int tid = threadIdx.x;
    int wave = tid >> 6, lane = tid & 63;
    int base = blockIdx.x * 64 + wave * 16;
    int m = lane & 15, kb = lane >> 4;
    f16x8 bfr[2][4];
#pragma unroll
    for (int kt = 0; kt < 2; ++kt)
#pragma unroll
        for (int nt = 0; nt < 4; ++nt) {
            I4H8 u;
            u.i4 = *(const int4*)(W2t + (nt * 16 + m) * HD + kt * 32 + kb * 8);
            bfr[kt][nt] = u.h8;
        }
    f16x8 afr[2];
    int anode = base + m;
#pragma unroll
    for (int kt = 0; kt < 2; ++kt) {
        I4H8 u;
        if (anode < NN)
            u.i4 = *(const int4*)(a2h + (size_t)anode * HD + kt * 32 + kb * 8);
        else
            u.i4 = make_int4(0, 0, 0, 0);
        afr[kt] = u.h8;
    }
    f32x4 acc[4] = {{0.f, 0.f, 0.f, 0.f}, {0.f, 0.f, 0.f, 0.f},
                    {0.f, 0.f, 0.f, 0.f}, {0.f, 0.f, 0.f, 0.f}};
#pragma unroll
    for (int kt = 0; kt < 2; ++kt)
#pragma unroll
        for (int nt = 0; nt < 4; ++nt)
            acc[nt] = __builtin_amdgcn_mfma_f32_16x16x32_f16(afr[kt], bfr[kt][nt], acc[nt], 0, 0, 0);
    int r0 = base + kb * 4;
    float dv[4];
    int bg[4];
#pragma unroll
    for (int r = 0; r < 4; ++r) {
        int node = r0 + r;
        dv[r] = (node < NN) ? dinv[node] : 0.f;
        bg[r] = (node < NN) ? batch[node] : -1;
    }
#pragma unroll
    for (int nt = 0; nt < 4; ++nt) {
        int n = nt * 16 + m;
        float bv = b2[n];
        int g = -1;
        float accf = 0.f;
#pragma unroll
        for (int r = 0; r < 4; ++r) {
            if (bg[r] < 0) break;
            float v = fmaxf(fmaf(dv[r], acc[nt][r], bv), 0.f);
            if (bg[r] != g) {
                if (g >= 0) atomicAdd(&pool[g * HD + n], accf);
                accf = 0.f; g = bg[r];
            }
            accf += v;
        }
        if (g >= 0) atomicAdd(&pool[g * HD + n], accf);
    }
}

__device__ __forceinline__ int lb_dev(const int* __restrict__ b, int n, int key) {
    int lo = 0, hi = n;
    while (lo < hi) {
        int mid = (lo + hi) >> 1;
        if (b[mid] < key) lo = mid + 1; else hi = mid;
    }
    return lo;
}

__global__ void final_k(const float* __restrict__ pool, const int* __restrict__ batch,
                        const float* __restrict__ Wlin, const float* __restrict__ blin,
                        float* __restrict__ out) {
    int g = blockIdx.x;
    int lane = threadIdx.x;
    int lo = lb_dev(batch, NN, g);
    int hi = lb_dev(batch, NN, g + 1);
    float cnt = (float)(hi - lo);
    float v = pool[g * HD + lane] * Wlin[lane];
#pragma unroll
    for (int off = 32; off > 0; off >>= 1) v += __shfl_down(v, off);
    if (lane == 0) out[g] = v / fmaxf(cnt, 1.0f) + blin[0];
}

// ---------------- launch ----------------

extern "C" void kernel_launch(void* const* d_in, const int* in_sizes, int n_in,
                              void* d_out, int out_size, void* d_ws, size_t ws_size,
                              hipStream_t stream) {
    const float* x    = (const float*)d_in[0];
    const int*   ei   = (const int*)d_in[1];
    const int*   bat  = (const int*)d_in[2];
    const float* W1   = (const float*)d_in[3];
    const float* b1   = (const float*)d_in[4];
    const float* W2   = (const float*)d_in[5];
    const float* b2   = (const float*)d_in[6];
    const float* Wlin = (const float*)d_in[7];
    const float* blin = (const float*)d_in[8];
    float* out = (float*)d_out;

    const int* src = ei;
    const int* dst = ei + NE;

    char* ws = (char*)d_ws;
    size_t off = 0;
    auto alloc = [&](size_t bytes) {
        char* p = ws + off;
        off += (bytes + 255) & ~(size_t)255;
        return p;
    };
    int*   bcur    = (int*)  alloc((NBUK + 1) * sizeof(int));
    int*   row_beg = (int*)  alloc(NN * sizeof(int));
    int*   row_deg = (int*)  alloc(NN * sizeof(int));
    float* dinv    = (float*)alloc(NN * sizeof(float));
    unsigned int* edges2 = (unsigned int*)alloc((size_t)NBUK * CAP * sizeof(unsigned int)); // 14.4 MB
    float4* xs     = (float4*)alloc((size_t)NN * sizeof(float4));
    __half* h1     = (__half*)alloc((size_t)NN * HD * sizeof(__half));
    __half* a2h    = (__half*)alloc((size_t)NN * HD * sizeof(__half));
    _Float16* W2t  = (_Float16*)alloc(HD * HD * sizeof(_Float16));
    float* pool    = (float*)alloc((size_t)NG * HD * sizeof(float));
    (void)ws_size; (void)n_in; (void)in_sizes; (void)out_size;

    const int BLK = 256;
    const int gW = (NN * 64 + BLK - 1) / BLK;   // one wave per node (256-thread blocks)

    // setup (cursors + W2t + pool zero) -> bucket runs -> in-place fine sort
    setup_k<<<(NG * HD + 255) / 256, 256, 0, stream>>>(bcur, W2, W2t, pool);
    stageA_k<<<NB, 512, 0, stream>>>(src, dst, bcur, edges2);
    build1_k<<<NBUK, 512, 0, stream>>>(bcur, (const float4*)x, edges2,
                                       row_beg, row_deg, dinv, xs);

    // layer 1 fused: gather + W1 GEMM -> fp16 h1
    g1f_k<<<gW, BLK, 0, stream>>>(xs, edges2, row_beg, row_deg, dinv, W1, b1, h1);

    // layer 2: wide-load gather, fp16 packed accumulation -> fp16 a2 (512-thread blocks)
    gather2_k<<<(NN * 64 + 511) / 512, 512, 0, stream>>>(h1, edges2, row_beg, row_deg, a2h);

    // combine + pool + readout (MFMA GEMM, 64 nodes per block)
    c2mfma_k<<<(NN + 63) / 64, 256, 0, stream>>>(a2h, W2t, b2, dinv, bat, pool);
    final_k<<<NG, 64, 0, stream>>>(pool, bat, Wlin, blin, out);
}

// Round 23
// 171.426 us; speedup vs baseline: 1.4406x; 1.0057x over previous
//
#include <hip/hip_runtime.h>
#include <hip/hip_fp16.h>

#define NN 100000
#define NE 3200000
#define NG 2048
#define HD 64
#define BUKSZ 256         // nodes per bucket
#define NBUK 391          // ceil(NN / BUKSZ)
#define NB 512            // stage blocks
#define CHUNK 6250        // NE / NB exactly
#define CAP 9216          // padded edge capacity per bucket

// NOTE: int LDS atomics only. Float LDS atomicAdd is a CAS loop (R8: 1342us).
// NOTE2 (R9): latency-bound gathers want max independent waves; 256-thd blocks
// beat 512 for gather2 (R22: 55.3 vs 53.9us).
// NOTE3 (R11): shfl with divergent srcLane under divergent bounds is undefined.
//   All-lanes-active uniform shfl (__shfl_up/xor, const operand) is safe.
// NOTE4 (R15): 16B/lane loads: 4 rows per VMEM instr.
// NOTE5 (R16): >16-float per-thread arrays spill to scratch (205MB = 60us).
// NOTE6 (R17): readlane-GEMM is VALU-issue-bound; MFMA = 8 ops/wave (R18: -28us).
// NOTE7 (R19): packed fp16 accumulation removes cvt from gather inner loop.
// NOTE8 (R20): chunk-per-XCD gather fixed FETCH (158->50MB) but 4x per-node
// overhead made it 2.4x slower. Gather pinned ~54us by 8-XCD L2 replication
// (mandatory ~102MB refetch of the 12.8MB h1); floor ~48us, escapes cost more.

typedef __attribute__((ext_vector_type(8))) _Float16 f16x8;
typedef __attribute__((ext_vector_type(4))) float f32x4;
union I4H8 { int4 i4; f16x8 h8; };

// ---------------- setup: bucket cursors + W2 transpose/convert + pool zero ----------------

__global__ void setup_k(int* __restrict__ bcur, const float* __restrict__ W2,
                        _Float16* __restrict__ W2t, float* __restrict__ pool) {
    int t = blockIdx.x * blockDim.x + threadIdx.x;
    if (t < NG * HD) pool[t] = 0.f;
    if (t < HD * HD) {
        int n = t >> 6, k = t & 63;
        W2t[n * HD + k] = (_Float16)W2[k * HD + n];
    }
    if (t <= NBUK) bcur[t] = t * CAP;
}

// ---------------- pass 1: block-local bucket sort -> padded bucket runs ----------------
// packed value: (dst & 255) << 17 | src   (src < 2^17)
// scan: per-wave shfl_up inclusive scan + single-thread wave-sum combine (2 barriers)

__global__ __launch_bounds__(512) void stageA_k(
        const int* __restrict__ src, const int* __restrict__ dst,
        int* __restrict__ bcur, unsigned int* __restrict__ edges2) {
    __shared__ int hist[NBUK];
    __shared__ int exb[NBUK + 1];
    __shared__ int cur[NBUK];
    __shared__ int obase[NBUK];
    __shared__ int wsum[8];
    __shared__ int wpre[8];
    __shared__ unsigned int svals[CHUNK];
    __shared__ unsigned short sbuk[CHUNK];   // bucket id per sorted slot
    int b = blockIdx.x, t = threadIdx.x;
    int lane = t & 63, wv = t >> 6;
    int base = b * CHUNK;
    for (int i = t; i < NBUK; i += 512) hist[i] = 0;
    __syncthreads();
    for (int i = t; i < CHUNK; i += 512)
        atomicAdd(&hist[dst[base + i] >> 8], 1);
    __syncthreads();
    int v = (t < NBUK) ? hist[t] : 0;
    int x = v;
#pragma unroll
    for (int o = 1; o < 64; o <<= 1) {
        int y = __shfl_up(x, o);
        if (lane >= o) x += y;
    }
    if (lane == 63) wsum[wv] = x;
    __syncthreads();
    if (t == 0) {
        int s = 0;
#pragma unroll
        for (int i = 0; i < 8; ++i) { wpre[i] = s; s += wsum[i]; }
    }
    __syncthreads();
    int excl = x - v + wpre[wv];
    if (t < NBUK) {
        exb[t] = excl;
        cur[t] = excl;
        obase[t] = v ? atomicAdd(&bcur[t], v) : 0;
    }
    if (t == 0) exb[NBUK] = CHUNK;
    __syncthreads();
    for (int i = t; i < CHUNK; i += 512) {
        int d = dst[base + i];
        int s = src[base + i];
        int bk = d >> 8;
        int pos = atomicAdd(&cur[bk], 1);
        svals[pos] = ((unsigned int)(d & 255) << 17) | (unsigned int)s;
        sbuk[pos] = (unsigned short)bk;
    }
    __syncthreads();
    for (int i = t; i < CHUNK; i += 512) {
        int lo = (int)sbuk[i];
        edges2[obase[lo] + (i - exb[lo])] = svals[i];
    }
}

// ---------------- pass 2: per-bucket fine sort (in-place) + row info + dinv + xs ----------------
// scan over 256 degs: wave shfl_up scan + combine (2 barriers)

__global__ __launch_bounds__(512) void build1_k(
        const int* __restrict__ bcur, const float4* __restrict__ x,
        unsigned int* __restrict__ edges2, int* __restrict__ row_beg,
        int* __restrict__ row_deg, float* __restrict__ dinv,
        float4* __restrict__ xs) {
    __shared__ unsigned int ebuf[CAP];   // 36 KB
    __shared__ int deg[BUKSZ];
    __shared__ int cur[BUKSZ];
    __shared__ int wsum[8];
    __shared__ int wpre[8];
    int k = blockIdx.x, t = threadIdx.x;
    int lane = t & 63, wv = t >> 6;
    int base = k * CAP;
    int len = bcur[k] - base;
    if (t < BUKSZ) deg[t] = 0;
    __syncthreads();
    for (int i = t; i < len; i += 512) {
        unsigned int pv = edges2[base + i];
        ebuf[i] = pv;
        atomicAdd(&deg[pv >> 17], 1);
    }
    __syncthreads();
    int v = (t < BUKSZ) ? deg[t] : 0;
    int xsc = v;
#pragma unroll
    for (int o = 1; o < 64; o <<= 1) {
        int y = __shfl_up(xsc, o);
        if (lane >= o) xsc += y;
    }
    if (lane == 63) wsum[wv] = xsc;
    __syncthreads();
    if (t == 0) {
        int s = 0;
#pragma unroll
        for (int i = 0; i < 8; ++i) { wpre[i] = s; s += wsum[i]; }
    }
    __syncthreads();
    if (t < BUKSZ) {
        int excl = xsc - v + wpre[wv];
        cur[t] = excl;
        int node = k * BUKSZ + t;
        if (node < NN) {
            row_beg[node] = base + excl;
            row_deg[node] = v;
            float di = rsqrtf((float)v + 1.0f);
            dinv[node] = di;
            float4 xv = x[node];
            xs[node] = make_float4(xv.x * di, xv.y * di, xv.z * di, xv.w * di);
        }
    }
    __syncthreads();
    for (int i = t; i < len; i += 512) {
        unsigned int pv = ebuf[i];
        int pos = atomicAdd(&cur[pv >> 17], 1);
        edges2[base + pos] = pv & 0x1FFFFu;
    }
}

// ---------------- layer 1 FUSED: wave-per-node gather + W1 GEMM -> fp16 h1 ----------------

__global__ __launch_bounds__(256) void g1f_k(
        const float4* __restrict__ xs, const unsigned int* __restrict__ csr,
        const int* __restrict__ row_beg, const int* __restrict__ row_deg,
        const float* __restrict__ dinv, const float* __restrict__ W1,
        const float* __restrict__ b1, __half* __restrict__ h1) {
    int wid = (blockIdx.x * blockDim.x + threadIdx.x) >> 6;
    int lane = threadIdx.x & 63;
    if (wid >= NN) return;
    int beg = row_beg[wid], deg = row_deg[wid];
    float sx = 0.f, sy = 0.f, sz = 0.f, sw = 0.f;
    for (int e = beg + lane; e < beg + deg; e += 64) {
        float4 w = xs[csr[e]];
        sx += w.x; sy += w.y; sz += w.z; sw += w.w;
    }
#pragma unroll
    for (int o = 1; o < 64; o <<= 1) {
        sx += __shfl_xor(sx, o);
        sy += __shfl_xor(sy, o);
        sz += __shfl_xor(sz, o);
        sw += __shfl_xor(sw, o);
    }
    float di = dinv[wid];
    float4 self = xs[wid];
    float ax = (sx + self.x) * di;
    float ay = (sy + self.y) * di;
    float az = (sz + self.z) * di;
    float aw = (sw + self.w) * di;
    float v = ax * W1[lane] + ay * W1[64 + lane] + az * W1[128 + lane] + aw * W1[192 + lane] + b1[lane];
    v = fmaxf(v, 0.f) * di;
    h1[(size_t)wid * HD + lane] = __float2half_rn(v);
}

// ---------------- layer 2 gather: wave per node; 16B/lane loads, fp16 packed accum ----------------

union H8 { int4 i4; __half2 h2[4]; };

__device__ __forceinline__ __half2 shfl_xor_h2(__half2 a, int m) {
    int v = *(int*)&a;
    int s = __shfl_xor(v, m);
    return *(__half2*)&s;
}

__global__ __launch_bounds__(256) void gather2_k(
        const __half* __restrict__ h1, const unsigned int* __restrict__ csr,
        const int* __restrict__ row_beg, const int* __restrict__ row_deg,
        __half* __restrict__ a2h) {
    __shared__ int sidx[4][64];          // per-wave index slice (wave-private)
    int wv = threadIdx.x >> 6;
    int wid = (blockIdx.x * blockDim.x + threadIdx.x) >> 6;
    int lane = threadIdx.x & 63;
    if (wid >= NN) return;
    int half = lane >> 5;
    int g = (lane >> 3) & 3;
    int sub = lane & 7;
    int hg = half * 4 + g;               // edge slot 0..7 within an 8-edge block
    int beg = row_beg[wid], deg = row_deg[wid];
    __half2 acc[4];
#pragma unroll
    for (int j = 0; j < 4; ++j) acc[j] = __half2half2(__float2half(0.f));
    int done = 0;
    while (done < deg) {
        int chunk = deg - done;
        if (chunk > 64) chunk = 64;
        if (lane < chunk) sidx[wv][lane] = (int)csr[beg + done + lane];  // 1 coalesced load
        int kb = 0;
        for (; kb + 31 < chunk; kb += 32) {      // 32 edges: 4 x 16B loads/lane
            int e0 = sidx[wv][kb + hg];
            int e1 = sidx[wv][kb + hg + 8];
            int e2 = sidx[wv][kb + hg + 16];
            int e3 = sidx[wv][kb + hg + 24];
            H8 r0, r1, r2, r3;
            r0.i4 = *(const int4*)(h1 + (size_t)e0 * HD + sub * 8);
            r1.i4 = *(const int4*)(h1 + (size_t)e1 * HD + sub * 8);
            r2.i4 = *(const int4*)(h1 + (size_t)e2 * HD + sub * 8);
            r3.i4 = *(const int4*)(h1 + (size_t)e3 * HD + sub * 8);
#pragma unroll
            for (int j = 0; j < 4; ++j) {
                acc[j] = __hadd2(acc[j], __hadd2(__hadd2(r0.h2[j], r1.h2[j]),
                                                 __hadd2(r2.h2[j], r3.h2[j])));
            }
        }
        for (; kb + 7 < chunk; kb += 8) {        // 8 edges: 1 load/lane
            int e0 = sidx[wv][kb + hg];
            H8 r0;
            r0.i4 = *(const int4*)(h1 + (size_t)e0 * HD + sub * 8);
#pragma unroll
            for (int j = 0; j < 4; ++j) acc[j] = __hadd2(acc[j], r0.h2[j]);
        }
        if (kb < chunk) {                        // tail <8: predicated per 8-lane group
            int e = kb + hg;
            if (e < chunk) {
                int e0 = sidx[wv][e];
                H8 r0;
                r0.i4 = *(const int4*)(h1 + (size_t)e0 * HD + sub * 8);
#pragma unroll
                for (int j = 0; j < 4; ++j) acc[j] = __hadd2(acc[j], r0.h2[j]);
            }
        }
        done += chunk;
    }
    // reduce across groups (xor 8,16) and halves (xor 32); uniform, all lanes active
#pragma unroll
    for (int j = 0; j < 4; ++j) {
        acc[j] = __hadd2(acc[j], shfl_xor_h2(acc[j], 8));
        acc[j] = __hadd2(acc[j], shfl_xor_h2(acc[j], 16));
        acc[j] = __hadd2(acc[j], shfl_xor_h2(acc[j], 32));
    }
    if (half == 0 && g == 0) {               // 8 lanes write the 128B row
        H8 sv, o;
        sv.i4 = *(const int4*)(h1 + (size_t)wid * HD + sub * 8);
#pragma unroll
        for (int j = 0; j < 4; ++j) o.h2[j] = __hadd2(acc[j], sv.h2[j]);
        ((int4*)a2h)[(size_t)wid * 8 + sub] = o.i4;
    }
}

// ---------------- combine2 + pool via MFMA: wave = 16 nodes, 8 mfma ----------------
// D[m][n] = sum_k a2[base+m][k] * W2[k][n]; A lane: m=lane&15, k=(lane>>4)*8+j.
// B from W2t[n][k]: n=lane&15, same k mapping. C/D: col=lane&15, row=(lane>>4)*4+reg.

__global__ __launch_bounds__(256) void c2mfma_k(
        const __half* __restrict__ a2h, const _Float16* __restrict__ W2t,
        const float* __restrict__ b2, const float* __restrict__ dinv,
        const int* __restrict__ batch, float* __restrict__ pool) {
    int tid = threadIdx.x;
    int wave = tid >> 6, lane = tid & 63;
    int base = blockIdx.x * 64 + wave * 16;
    int m = lane & 15, kb = lane >> 4;
    f16x8 bfr[2][4];
#pragma unroll
    for (int kt = 0; kt < 2; ++kt)
#pragma unroll
        for (int nt = 0; nt < 4; ++nt) {
            I4H8 u;
            u.i4 = *(const int4*)(W2t + (nt * 16 + m) * HD + kt * 32 + kb * 8);
            bfr[kt][nt] = u.h8;
        }
    f16x8 afr[2];
    int anode = base + m;
#pragma unroll
    for (int kt = 0; kt < 2; ++kt) {
        I4H8 u;
        if (anode < NN)
            u.i4 = *(const int4*)(a2h + (size_t)anode * HD + kt * 32 + kb * 8);
        else
            u.i4 = make_int4(0, 0, 0, 0);
        afr[kt] = u.h8;
    }
    f32x4 acc[4] = {{0.f, 0.f, 0.f, 0.f}, {0.f, 0.f, 0.f, 0.f},
                    {0.f, 0.f, 0.f, 0.f}, {0.f, 0.f, 0.f, 0.f}};
#pragma unroll
    for (int kt = 0; kt < 2; ++kt)
#pragma unroll
        for (int nt = 0; nt < 4; ++nt)
            acc[nt] = __builtin_amdgcn_mfma_f32_16x16x32_f16(afr[kt], bfr[kt][nt], acc[nt], 0, 0, 0);
    int r0 = base + kb * 4;
    float dv[4];
    int bg[4];
#pragma unroll
    for (int r = 0; r < 4; ++r) {
        int node = r0 + r;
        dv[r] = (node < NN) ? dinv[node] : 0.f;
        bg[r] = (node < NN) ? batch[node] : -1;
    }
#pragma unroll
    for (int nt = 0; nt < 4; ++nt) {
        int n = nt * 16 + m;
        float bv = b2[n];
        int g = -1;
        float accf = 0.f;
#pragma unroll
        for (int r = 0; r < 4; ++r) {
            if (bg[r] < 0) break;
            float v = fmaxf(fmaf(dv[r], acc[nt][r], bv), 0.f);
            if (bg[r] != g) {
                if (g >= 0) atomicAdd(&pool[g * HD + n], accf);
                accf = 0.f; g = bg[r];
            }
            accf += v;
        }
        if (g >= 0) atomicAdd(&pool[g * HD + n], accf);
    }
}

__device__ __forceinline__ int lb_dev(const int* __restrict__ b, int n, int key) {
    int lo = 0, hi = n;
    while (lo < hi) {
        int mid = (lo + hi) >> 1;
        if (b[mid] < key) lo = mid + 1; else hi = mid;
    }
    return lo;
}

__global__ void final_k(const float* __restrict__ pool, const int* __restrict__ batch,
                        const float* __restrict__ Wlin, const float* __restrict__ blin,
                        float* __restrict__ out) {
    int g = blockIdx.x;
    int lane = threadIdx.x;
    int lo = lb_dev(batch, NN, g);
    int hi = lb_dev(batch, NN, g + 1);
    float cnt = (float)(hi - lo);
    float v = pool[g * HD + lane] * Wlin[lane];
#pragma unroll
    for (int off = 32; off > 0; off >>= 1) v += __shfl_down(v, off);
    if (lane == 0) out[g] = v / fmaxf(cnt, 1.0f) + blin[0];
}

// ---------------- launch ----------------

extern "C" void kernel_launch(void* const* d_in, const int* in_sizes, int n_in,
                              void* d_out, int out_size, void* d_ws, size_t ws_size,
                              hipStream_t stream) {
    const float* x    = (const float*)d_in[0];
    const int*   ei   = (const int*)d_in[1];
    const int*   bat  = (const int*)d_in[2];
    const float* W1   = (const float*)d_in[3];
    const float* b1   = (const float*)d_in[4];
    const float* W2   = (const float*)d_in[5];
    const float* b2   = (const float*)d_in[6];
    const float* Wlin = (const float*)d_in[7];
    const float* blin = (const float*)d_in[8];
    float* out = (float*)d_out;

    const int* src = ei;
    const int* dst = ei + NE;

    char* ws = (char*)d_ws;
    size_t off = 0;
    auto alloc = [&](size_t bytes) {
        char* p = ws + off;
        off += (bytes + 255) & ~(size_t)255;
        return p;
    };
    int*   bcur    = (int*)  alloc((NBUK + 1) * sizeof(int));
    int*   row_beg = (int*)  alloc(NN * sizeof(int));
    int*   row_deg = (int*)  alloc(NN * sizeof(int));
    float* dinv    = (float*)alloc(NN * sizeof(float));
    unsigned int* edges2 = (unsigned int*)alloc((size_t)NBUK * CAP * sizeof(unsigned int)); // 14.4 MB
    float4* xs     = (float4*)alloc((size_t)NN * sizeof(float4));
    __half* h1     = (__half*)alloc((size_t)NN * HD * sizeof(__half));
    __half* a2h    = (__half*)alloc((size_t)NN * HD * sizeof(__half));
    _Float16* W2t  = (_Float16*)alloc(HD * HD * sizeof(_Float16));
    float* pool    = (float*)alloc((size_t)NG * HD * sizeof(float));
    (void)ws_size; (void)n_in; (void)in_sizes; (void)out_size;

    const int BLK = 256;
    const int gW = (NN * 64 + BLK - 1) / BLK;   // one wave per node (256-thread blocks)

    // setup (cursors + W2t + pool zero) -> bucket runs -> in-place fine sort
    setup_k<<<(NG * HD + 255) / 256, 256, 0, stream>>>(bcur, W2, W2t, pool);
    stageA_k<<<NB, 512, 0, stream>>>(src, dst, bcur, edges2);
    build1_k<<<NBUK, 512, 0, stream>>>(bcur, (const float4*)x, edges2,
                                       row_beg, row_deg, dinv, xs);

    // layer 1 fused: gather + W1 GEMM -> fp16 h1
    g1f_k<<<gW, BLK, 0, stream>>>(xs, edges2, row_beg, row_deg, dinv, W1, b1, h1);

    // layer 2: wide-load gather, fp16 packed accumulation -> fp16 a2
    gather2_k<<<gW, BLK, 0, stream>>>(h1, edges2, row_beg, row_deg, a2h);

    // combine + pool + readout (MFMA GEMM, 64 nodes per block)
    c2mfma_k<<<(NN + 63) / 64, 256, 0, stream>>>(a2h, W2t, b2, dinv, bat, pool);
    final_k<<<NG, 64, 0, stream>>>(pool, bat, Wlin, blin, out);
}